// Round 1
// baseline (672.300 us; speedup 1.0000x reference)
//
#include <hip/hip_runtime.h>
#include <hip/hip_bf16.h>
#include <stdint.h>
#include <stddef.h>

typedef __bf16 bf16;
typedef __bf16 bf16x4 __attribute__((ext_vector_type(4)));
typedef __bf16 bf16x8 __attribute__((ext_vector_type(8)));
typedef float f32x4 __attribute__((ext_vector_type(4)));

#define BROWS 16384
#define NDIM 1024
#define NLAYERS 3
#define NEXP 8
#define RDIM 64

// ---------------------------------------------------------------------------
// async global->LDS, 16B per lane. dst must be wave-uniform base (HW adds lane*16).
__device__ __forceinline__ void gld_lds16(const bf16* g, bf16* l) {
    __builtin_amdgcn_global_load_lds(
        (const __attribute__((address_space(1))) void*)g,
        (__attribute__((address_space(3))) void*)l, 16, 0, 0);
}

// ---------------------------------------------------------------------------
// Weight prep: V (fp32 [L,E,R,N] == [L,512,1024]) -> bf16 flat copy
__global__ __launch_bounds__(256) void cvt_bf16_kernel(
    const float* __restrict__ src, bf16* __restrict__ dst, int n4)
{
    int i = blockIdx.x * 256 + threadIdx.x;
    if (i < n4) {
        float4 v = ((const float4*)src)[i];
        bf16x4 b;
        b[0] = (bf16)v.x; b[1] = (bf16)v.y; b[2] = (bf16)v.z; b[3] = (bf16)v.w;
        ((bf16x4*)dst)[i] = b;
    }
}

// U (fp32 [L,E,N,R]) -> wu bf16 [L, N, E*R]  (transpose e <-> n)
__global__ __launch_bounds__(256) void wu_transpose_kernel(
    const float* __restrict__ U, bf16* __restrict__ wu)
{
    int d = blockIdx.x * 256 + threadIdx.x;      // 3*1024*512 = 1572864 total
    int r = d & 63;
    int e = (d >> 6) & 7;
    int n = (d >> 9) & 1023;
    int l = d >> 19;
    size_t s = (((size_t)(l * 8 + e)) * 1024 + n) * 64 + r;
    wu[d] = (bf16)U[s];
}

// ---------------------------------------------------------------------------
// gates[b,e] = softmax_e( x_l . gw[e] ), plus x_l -> bf16 copy (xb)
__global__ __launch_bounds__(256) void gates_xb_kernel(
    const float* __restrict__ xl, const float* __restrict__ gw,
    float* __restrict__ gates, bf16* __restrict__ xb)
{
    __shared__ float gs[NEXP * NDIM];   // 32 KB
    const int tid = threadIdx.x;
#pragma unroll
    for (int i = 0; i < 8; ++i) {
        int f = (i * 256 + tid) * 4;
        *(float4*)&gs[f] = *(const float4*)&gw[f];
    }
    __syncthreads();
    const int wv = tid >> 6, ln = tid & 63;
    const int row = blockIdx.x * 4 + wv;
    const float* xr = xl + (size_t)row * NDIM;
    bf16* xbr = xb + (size_t)row * NDIM;

    float acc[8] = {0, 0, 0, 0, 0, 0, 0, 0};
#pragma unroll
    for (int i = 0; i < 4; ++i) {
        int n0 = (i * 64 + ln) * 4;
        float4 xv = *(const float4*)&xr[n0];
        bf16x4 bv;
        bv[0] = (bf16)xv.x; bv[1] = (bf16)xv.y; bv[2] = (bf16)xv.z; bv[3] = (bf16)xv.w;
        *(bf16x4*)&xbr[n0] = bv;
#pragma unroll
        for (int e = 0; e < 8; ++e) {
            const float* g4 = &gs[e * NDIM + n0];
            acc[e] += xv.x * g4[0] + xv.y * g4[1] + xv.z * g4[2] + xv.w * g4[3];
        }
    }
#pragma unroll
    for (int e = 0; e < 8; ++e) {
        float v = acc[e];
#pragma unroll
        for (int m = 32; m >= 1; m >>= 1) v += __shfl_xor(v, m);
        acc[e] = v;
    }
    float mx = acc[0];
#pragma unroll
    for (int e = 1; e < 8; ++e) mx = fmaxf(mx, acc[e]);
    float s = 0.f;
#pragma unroll
    for (int e = 0; e < 8; ++e) { acc[e] = __expf(acc[e] - mx); s += acc[e]; }
    float inv = 1.0f / s;
    if (ln == 0) {
#pragma unroll
        for (int e = 0; e < 8; ++e) gates[(size_t)row * 8 + e] = acc[e] * inv;
    }
}

// ---------------------------------------------------------------------------
// per-expert R x R:  cp[b,(e,r)] = bf16( g[b,e] * relu( sum_s C[e,r,s]*rv[b,(e,s)] ) )
__global__ __launch_bounds__(256) void cexpert_kernel(
    const bf16* __restrict__ rv, const float* __restrict__ Cw,
    const float* __restrict__ gates, bf16* __restrict__ cp)
{
    const int e = blockIdx.y;
    __shared__ float Cs[64 * 65];
    const int tid = threadIdx.x;
#pragma unroll
    for (int i = 0; i < 16; ++i) {
        int f = i * 256 + tid;
        Cs[(f >> 6) * 65 + (f & 63)] = Cw[e * 4096 + f];
    }
    __syncthreads();
    const int wv = tid >> 6, ln = tid & 63;
    const size_t row0 = (size_t)blockIdx.x * 64 + wv * 16;
    for (int i = 0; i < 16; ++i) {
        size_t row = row0 + i;
        float rvv = (float)rv[row * 512 + e * 64 + ln];
        float c = 0.f;
#pragma unroll
        for (int s = 0; s < 64; ++s) c += Cs[ln * 65 + s] * __shfl(rvv, s);
        float g = gates[row * 8 + e];
        cp[row * 512 + e * 64 + ln] = (bf16)(fmaxf(c, 0.f) * g);
    }
}

// ---------------------------------------------------------------------------
// GEMM: out[M,N] = A[M,K] * Bt[N,K]^T   (bf16 in, fp32 acc)
// MODE 0: rv_out = bf16(relu(acc))            (Ntot = 512)
// MODE 1: out = xl + x0*(acc + bias[col])     (Ntot = 1024, fp32, in-place ok)
template<int KDIM, int MODE>
__global__ __launch_bounds__(256) void gemm_kernel(
    const bf16* __restrict__ A, const bf16* __restrict__ Bt,
    bf16* __restrict__ rv_out,
    const float* __restrict__ xl, const float* __restrict__ x0,
    const float* __restrict__ bias, float* __restrict__ out, int Ntot)
{
    __shared__ __align__(16) bf16 As[128 * 64];
    __shared__ __align__(16) bf16 Bs[128 * 64];
    const int tid = threadIdx.x;
    const int wv = tid >> 6, ln = tid & 63;
    const long bm = (long)blockIdx.y * 128;
    const long bn = (long)blockIdx.x * 128;
    const int wm = (wv >> 1) << 6, wn = (wv & 1) << 6;
    f32x4 acc[4][4] = {};

    const int srow = tid >> 3;           // staging row within chunk 0
    const int scol = (tid & 7) * 8;      // staging col (bf16 elems)
    const bf16* Abase = A + (bm + srow) * (long)KDIM + scol;
    const bf16* Bbase = Bt + (bn + srow) * (long)KDIM + scol;
    bf16* Asl = &As[(tid & ~63) * 8];    // wave-uniform LDS dst base
    bf16* Bsl = &Bs[(tid & ~63) * 8];

    for (int kt = 0; kt < KDIM / 64; ++kt) {
        const int k0 = kt * 64;
        __syncthreads();
#pragma unroll
        for (int t = 0; t < 4; ++t) {
            gld_lds16(Abase + (long)t * 32 * KDIM + k0, Asl + t * 2048);
            gld_lds16(Bbase + (long)t * 32 * KDIM + k0, Bsl + t * 2048);
        }
        __syncthreads();
#pragma unroll
        for (int kc = 0; kc < 2; ++kc) {
            bf16x8 af[4], bfr[4];
#pragma unroll
            for (int i = 0; i < 4; ++i) {
                af[i]  = *(const bf16x8*)&As[(wm + i * 16 + (ln & 15)) * 64 + kc * 32 + (ln >> 4) * 8];
                bfr[i] = *(const bf16x8*)&Bs[(wn + i * 16 + (ln & 15)) * 64 + kc * 32 + (ln >> 4) * 8];
            }
#pragma unroll
            for (int mi = 0; mi < 4; ++mi)
#pragma unroll
                for (int ni = 0; ni < 4; ++ni)
                    acc[mi][ni] = __builtin_amdgcn_mfma_f32_16x16x32_bf16(
                        af[mi], bfr[ni], acc[mi][ni], 0, 0, 0);
        }
    }

    const int cr = (ln >> 4) * 4, cc = ln & 15;
    if (MODE == 0) {
#pragma unroll
        for (int mi = 0; mi < 4; ++mi)
#pragma unroll
            for (int ni = 0; ni < 4; ++ni) {
                long col = bn + wn + ni * 16 + cc;
#pragma unroll
                for (int j = 0; j < 4; ++j) {
                    long row = bm + wm + mi * 16 + cr + j;
                    rv_out[row * (long)Ntot + col] = (bf16)fmaxf(acc[mi][ni][j], 0.f);
                }
            }
    } else {
#pragma unroll
        for (int mi = 0; mi < 4; ++mi)
#pragma unroll
            for (int ni = 0; ni < 4; ++ni) {
                long col = bn + wn + ni * 16 + cc;
                float bcol = bias[col];
#pragma unroll
                for (int j = 0; j < 4; ++j) {
                    long row = bm + wm + mi * 16 + cr + j;
                    long idx = row * (long)Ntot + col;
                    out[idx] = xl[idx] + x0[idx] * (acc[mi][ni][j] + bcol);
                }
            }
    }
}

// ---------------------------------------------------------------------------
extern "C" void kernel_launch(void* const* d_in, const int* in_sizes, int n_in,
                              void* d_out, int out_size, void* d_ws, size_t ws_size,
                              hipStream_t stream)
{
    const float* x0   = (const float*)d_in[0];
    const float* U    = (const float*)d_in[1];
    const float* V    = (const float*)d_in[2];
    const float* Cw   = (const float*)d_in[3];
    const float* bias = (const float*)d_in[4];
    const float* gw   = (const float*)d_in[5];
    float* out = (float*)d_out;

    char* ws = (char*)d_ws;
    bf16*  wv    = (bf16*)ws;                                   // 3*512*1024 bf16 = 3 MB
    bf16*  wu    = (bf16*)(ws + 3145728);                       // 3 MB
    bf16*  xb    = (bf16*)(ws + 6291456);                       // 16384*1024 bf16 = 32 MB
    bf16*  rv    = (bf16*)(ws + 6291456 + 33554432);            // 16 MB
    bf16*  cp    = (bf16*)(ws + 6291456 + 33554432 + 16777216); // 16 MB
    float* gates = (float*)(ws + 6291456 + 33554432 + 2 * 16777216); // 512 KB

    // weight prep (every call; same work each call)
    cvt_bf16_kernel<<<1536, 256, 0, stream>>>(V, wv, 393216);
    wu_transpose_kernel<<<6144, 256, 0, stream>>>(U, wu);

    for (int l = 0; l < NLAYERS; ++l) {
        const float* xl = (l == 0) ? x0 : out;   // x_l lives in d_out after layer 1
        gates_xb_kernel<<<4096, 256, 0, stream>>>(xl, gw, gates, xb);
        gemm_kernel<1024, 0><<<dim3(4, 128), 256, 0, stream>>>(
            xb, wv + (size_t)l * 524288, rv, nullptr, nullptr, nullptr, nullptr, 512);
        cexpert_kernel<<<dim3(256, 8), 256, 0, stream>>>(
            rv, Cw + (size_t)l * 32768, gates, cp);
        gemm_kernel<512, 1><<<dim3(8, 128), 256, 0, stream>>>(
            cp, wu + (size_t)l * 524288, nullptr, xl, x0, bias + (size_t)l * 1024, out, 1024);
    }
}

// Round 2
// 408.981 us; speedup vs baseline: 1.6438x; 1.6438x over previous
//
#include <hip/hip_runtime.h>
#include <hip/hip_bf16.h>
#include <stdint.h>
#include <stddef.h>

typedef __bf16 bf16;
typedef __bf16 bf16x4 __attribute__((ext_vector_type(4)));
typedef __bf16 bf16x8 __attribute__((ext_vector_type(8)));
typedef float f32x4 __attribute__((ext_vector_type(4)));

#define BROWS 16384
#define NDIM 1024
#define NLAYERS 3
#define NEXP 8
#define RDIM 64

// ---------------------------------------------------------------------------
// async global->LDS, 16B per lane. dst must be wave-uniform base (HW adds lane*16).
__device__ __forceinline__ void gld_lds16(const bf16* g, bf16* l) {
    __builtin_amdgcn_global_load_lds(
        (const __attribute__((address_space(1))) void*)g,
        (__attribute__((address_space(3))) void*)l, 16, 0, 0);
}

// ---------------------------------------------------------------------------
// Weight prep: V (fp32 [L,E,R,N] == [L,512,1024]) -> bf16 flat copy
__global__ __launch_bounds__(256) void cvt_bf16_kernel(
    const float* __restrict__ src, bf16* __restrict__ dst, int n4)
{
    int i = blockIdx.x * 256 + threadIdx.x;
    if (i < n4) {
        float4 v = ((const float4*)src)[i];
        bf16x4 b;
        b[0] = (bf16)v.x; b[1] = (bf16)v.y; b[2] = (bf16)v.z; b[3] = (bf16)v.w;
        ((bf16x4*)dst)[i] = b;
    }
}

// U (fp32 [L,E,N,R]) -> wu bf16 [L, N, E*R]  (transpose e <-> n)
__global__ __launch_bounds__(256) void wu_transpose_kernel(
    const float* __restrict__ U, bf16* __restrict__ wu)
{
    int d = blockIdx.x * 256 + threadIdx.x;      // 3*1024*512 = 1572864 total
    int r = d & 63;
    int e = (d >> 6) & 7;
    int n = (d >> 9) & 1023;
    int l = d >> 19;
    size_t s = (((size_t)(l * 8 + e)) * 1024 + n) * 64 + r;
    wu[d] = (bf16)U[s];
}

// ---------------------------------------------------------------------------
// gates[b,e] = softmax_e( x_l . gw[e] ), plus x_l -> bf16 copy (xb)
__global__ __launch_bounds__(256) void gates_xb_kernel(
    const float* __restrict__ xl, const float* __restrict__ gw,
    float* __restrict__ gates, bf16* __restrict__ xb)
{
    __shared__ float gs[NEXP * NDIM];   // 32 KB
    const int tid = threadIdx.x;
#pragma unroll
    for (int i = 0; i < 8; ++i) {
        int f = (i * 256 + tid) * 4;
        *(float4*)&gs[f] = *(const float4*)&gw[f];
    }
    __syncthreads();
    const int wv = tid >> 6, ln = tid & 63;
    const int row = blockIdx.x * 4 + wv;
    const float* xr = xl + (size_t)row * NDIM;
    bf16* xbr = xb + (size_t)row * NDIM;

    float acc[8] = {0, 0, 0, 0, 0, 0, 0, 0};
#pragma unroll
    for (int i = 0; i < 4; ++i) {
        int n0 = (i * 64 + ln) * 4;
        float4 xv = *(const float4*)&xr[n0];
        bf16x4 bv;
        bv[0] = (bf16)xv.x; bv[1] = (bf16)xv.y; bv[2] = (bf16)xv.z; bv[3] = (bf16)xv.w;
        *(bf16x4*)&xbr[n0] = bv;
#pragma unroll
        for (int e = 0; e < 8; ++e) {
            const float* g4 = &gs[e * NDIM + n0];
            acc[e] += xv.x * g4[0] + xv.y * g4[1] + xv.z * g4[2] + xv.w * g4[3];
        }
    }
#pragma unroll
    for (int e = 0; e < 8; ++e) {
        float v = acc[e];
#pragma unroll
        for (int m = 32; m >= 1; m >>= 1) v += __shfl_xor(v, m);
        acc[e] = v;
    }
    float mx = acc[0];
#pragma unroll
    for (int e = 1; e < 8; ++e) mx = fmaxf(mx, acc[e]);
    float s = 0.f;
#pragma unroll
    for (int e = 0; e < 8; ++e) { acc[e] = __expf(acc[e] - mx); s += acc[e]; }
    float inv = 1.0f / s;
    if (ln == 0) {
#pragma unroll
        for (int e = 0; e < 8; ++e) gates[(size_t)row * 8 + e] = acc[e] * inv;
    }
}

// ---------------------------------------------------------------------------
// Fused GEMM + per-expert C-chain:
//   v   = xb @ wv^T              (128x128 block tile; wave tile 64x64 = 1 expert)
//   cp  = bf16( gates[:,e] * relu( relu(v) @ C[e]^T ) )   written directly
template<int KDIM>
__global__ __launch_bounds__(256) void gemm_vc_kernel(
    const bf16* __restrict__ A, const bf16* __restrict__ Bt,
    const float* __restrict__ Cwl, const float* __restrict__ gates,
    bf16* __restrict__ cp)
{
    // As 8192 | Bs 8192 | Cs 8192 bf16 elems = 48 KB. vs aliases As+Bs.
    __shared__ __align__(16) bf16 smem[24576];
    bf16* As = smem;
    bf16* Bs = smem + 8192;
    bf16* Cs = smem + 16384;

    const int tid = threadIdx.x;
    const int wv = tid >> 6, ln = tid & 63;
    const long bm = (long)blockIdx.y * 128;
    const long bn = (long)blockIdx.x * 128;
    const int wm = (wv >> 1) << 6, wn = (wv & 1) << 6;
    const int e_loc = wv & 1;                      // which of the block's 2 experts
    f32x4 acc[4][4] = {};

    // ---- stage C weights for this block's 2 experts (fp32 -> bf16, XOR-swizzled [r][s])
    {
        const float* Cg = Cwl + (size_t)(blockIdx.x * 2) * 4096;
#pragma unroll
        for (int i = 0; i < 8; ++i) {
            int f = tid * 32 + i * 4;              // 4 consecutive s, same r
            float4 cv = *(const float4*)&Cg[f];
            int ee = f >> 12;
            int r  = (f >> 6) & 63;
            int s  = f & 63;
            bf16x4 b;
            b[0] = (bf16)cv.x; b[1] = (bf16)cv.y; b[2] = (bf16)cv.z; b[3] = (bf16)cv.w;
            char* base = (char*)Cs + ee * 8192;
            *(bf16x4*)(base + ((r * 128 + s * 2) ^ ((r & 7) << 4))) = b;
        }
    }

    const int srow = tid >> 3;
    const int scol = (tid & 7) * 8;
    const bf16* Abase = A + (bm + srow) * (long)KDIM + scol;
    const bf16* Bbase = Bt + (bn + srow) * (long)KDIM + scol;
    bf16* Asl = &As[(tid & ~63) * 8];
    bf16* Bsl = &Bs[(tid & ~63) * 8];

    for (int kt = 0; kt < KDIM / 64; ++kt) {
        const int k0 = kt * 64;
        __syncthreads();
#pragma unroll
        for (int t = 0; t < 4; ++t) {
            gld_lds16(Abase + (long)t * 32 * KDIM + k0, Asl + t * 2048);
            gld_lds16(Bbase + (long)t * 32 * KDIM + k0, Bsl + t * 2048);
        }
        __syncthreads();
#pragma unroll
        for (int kc = 0; kc < 2; ++kc) {
            bf16x8 af[4], bfr[4];
#pragma unroll
            for (int i = 0; i < 4; ++i) {
                af[i]  = *(const bf16x8*)&As[(wm + i * 16 + (ln & 15)) * 64 + kc * 32 + (ln >> 4) * 8];
                bfr[i] = *(const bf16x8*)&Bs[(wn + i * 16 + (ln & 15)) * 64 + kc * 32 + (ln >> 4) * 8];
            }
#pragma unroll
            for (int mi = 0; mi < 4; ++mi)
#pragma unroll
                for (int ni = 0; ni < 4; ++ni)
                    acc[mi][ni] = __builtin_amdgcn_mfma_f32_16x16x32_bf16(
                        af[mi], bfr[ni], acc[mi][ni], 0, 0, 0);
        }
    }

    // ---- relu(v) -> per-wave 64x64 bf16 LDS tile (aliases As/Bs), XOR-swizzled
    __syncthreads();   // everyone done reading As/Bs
    char* vsb = (char*)smem + wv * 8192;
    const int cr = (ln >> 4) * 4, cc = ln & 15;
#pragma unroll
    for (int mi = 0; mi < 4; ++mi)
#pragma unroll
        for (int ni = 0; ni < 4; ++ni)
#pragma unroll
            for (int j = 0; j < 4; ++j) {
                int row = mi * 16 + cr + j;
                int col = ni * 16 + cc;
                *(bf16*)(vsb + ((row * 128 + col * 2) ^ ((row & 7) << 4))) =
                    (bf16)fmaxf(acc[mi][ni][j], 0.f);
            }
    __syncthreads();   // vs + Cs visible

    // ---- c = relu(v) @ C[e]^T   (64x64x64 per wave, 32 MFMAs)
    f32x4 acc2[4][4] = {};
    char* csb = (char*)Cs + e_loc * 8192;
#pragma unroll
    for (int kc = 0; kc < 2; ++kc) {
        bf16x8 af[4], bfr[4];
        const int sb = (kc * 32 + (ln >> 4) * 8) * 2;
#pragma unroll
        for (int i = 0; i < 4; ++i) {
            int ra = i * 16 + (ln & 15);
            af[i]  = *(const bf16x8*)(vsb + ((ra * 128 + sb) ^ ((ra & 7) << 4)));
            bfr[i] = *(const bf16x8*)(csb + ((ra * 128 + sb) ^ ((ra & 7) << 4)));
        }
#pragma unroll
        for (int mi = 0; mi < 4; ++mi)
#pragma unroll
            for (int ni = 0; ni < 4; ++ni)
                acc2[mi][ni] = __builtin_amdgcn_mfma_f32_16x16x32_bf16(
                    af[mi], bfr[ni], acc2[mi][ni], 0, 0, 0);
    }

    // ---- epilogue: cp = bf16( g * relu(c) )
    const int e_g = (int)(bn >> 6) + e_loc;
#pragma unroll
    for (int mi = 0; mi < 4; ++mi)
#pragma unroll
        for (int j = 0; j < 4; ++j) {
            long row = bm + wm + mi * 16 + cr + j;
            float g = gates[row * 8 + e_g];
#pragma unroll
            for (int ni = 0; ni < 4; ++ni) {
                long col = bn + wn + ni * 16 + cc;
                cp[row * 512 + col] = (bf16)(fmaxf(acc2[mi][ni][j], 0.f) * g);
            }
        }
}

// ---------------------------------------------------------------------------
// GEMM: out[M,N] = A[M,K] * Bt[N,K]^T, epilogue out = xl + x0*(acc + bias[col])
template<int KDIM>
__global__ __launch_bounds__(256) void gemm_kernel(
    const bf16* __restrict__ A, const bf16* __restrict__ Bt,
    const float* __restrict__ xl, const float* __restrict__ x0,
    const float* __restrict__ bias, float* __restrict__ out, int Ntot)
{
    __shared__ __align__(16) bf16 As[128 * 64];
    __shared__ __align__(16) bf16 Bs[128 * 64];
    const int tid = threadIdx.x;
    const int wv = tid >> 6, ln = tid & 63;
    const long bm = (long)blockIdx.y * 128;
    const long bn = (long)blockIdx.x * 128;
    const int wm = (wv >> 1) << 6, wn = (wv & 1) << 6;
    f32x4 acc[4][4] = {};

    const int srow = tid >> 3;
    const int scol = (tid & 7) * 8;
    const bf16* Abase = A + (bm + srow) * (long)KDIM + scol;
    const bf16* Bbase = Bt + (bn + srow) * (long)KDIM + scol;
    bf16* Asl = &As[(tid & ~63) * 8];
    bf16* Bsl = &Bs[(tid & ~63) * 8];

    for (int kt = 0; kt < KDIM / 64; ++kt) {
        const int k0 = kt * 64;
        __syncthreads();
#pragma unroll
        for (int t = 0; t < 4; ++t) {
            gld_lds16(Abase + (long)t * 32 * KDIM + k0, Asl + t * 2048);
            gld_lds16(Bbase + (long)t * 32 * KDIM + k0, Bsl + t * 2048);
        }
        __syncthreads();
#pragma unroll
        for (int kc = 0; kc < 2; ++kc) {
            bf16x8 af[4], bfr[4];
#pragma unroll
            for (int i = 0; i < 4; ++i) {
                af[i]  = *(const bf16x8*)&As[(wm + i * 16 + (ln & 15)) * 64 + kc * 32 + (ln >> 4) * 8];
                bfr[i] = *(const bf16x8*)&Bs[(wn + i * 16 + (ln & 15)) * 64 + kc * 32 + (ln >> 4) * 8];
            }
#pragma unroll
            for (int mi = 0; mi < 4; ++mi)
#pragma unroll
                for (int ni = 0; ni < 4; ++ni)
                    acc[mi][ni] = __builtin_amdgcn_mfma_f32_16x16x32_bf16(
                        af[mi], bfr[ni], acc[mi][ni], 0, 0, 0);
        }
    }

    const int cr = (ln >> 4) * 4, cc = ln & 15;
#pragma unroll
    for (int mi = 0; mi < 4; ++mi)
#pragma unroll
        for (int ni = 0; ni < 4; ++ni) {
            long col = bn + wn + ni * 16 + cc;
            float bcol = bias[col];
#pragma unroll
            for (int j = 0; j < 4; ++j) {
                long row = bm + wm + mi * 16 + cr + j;
                long idx = row * (long)Ntot + col;
                out[idx] = xl[idx] + x0[idx] * (acc[mi][ni][j] + bcol);
            }
        }
}

// ---------------------------------------------------------------------------
extern "C" void kernel_launch(void* const* d_in, const int* in_sizes, int n_in,
                              void* d_out, int out_size, void* d_ws, size_t ws_size,
                              hipStream_t stream)
{
    const float* x0   = (const float*)d_in[0];
    const float* U    = (const float*)d_in[1];
    const float* V    = (const float*)d_in[2];
    const float* Cw   = (const float*)d_in[3];
    const float* bias = (const float*)d_in[4];
    const float* gw   = (const float*)d_in[5];
    float* out = (float*)d_out;

    char* ws = (char*)d_ws;
    bf16*  wv    = (bf16*)ws;                                   // 3*512*1024 bf16 = 3 MB
    bf16*  wu    = (bf16*)(ws + 3145728);                       // 3 MB
    bf16*  xb    = (bf16*)(ws + 6291456);                       // 32 MB
    bf16*  cp    = (bf16*)(ws + 6291456 + 33554432);            // 16 MB
    float* gates = (float*)(ws + 6291456 + 33554432 + 16777216); // 512 KB

    // weight prep (every call; same work each call)
    cvt_bf16_kernel<<<1536, 256, 0, stream>>>(V, wv, 393216);
    wu_transpose_kernel<<<6144, 256, 0, stream>>>(U, wu);

    for (int l = 0; l < NLAYERS; ++l) {
        const float* xl = (l == 0) ? x0 : out;   // x_l lives in d_out after layer 1
        gates_xb_kernel<<<4096, 256, 0, stream>>>(xl, gw, gates, xb);
        gemm_vc_kernel<1024><<<dim3(4, 128), 256, 0, stream>>>(
            xb, wv + (size_t)l * 524288, Cw + (size_t)l * 32768, gates, cp);
        gemm_kernel<512><<<dim3(8, 128), 256, 0, stream>>>(
            cp, wu + (size_t)l * 524288, xl, x0, bias + (size_t)l * 1024, out, 1024);
    }
}